// Round 1
// baseline (132.590 us; speedup 1.0000x reference)
//
#include <hip/hip_runtime.h>

#define TPB   256
#define SLICE 512
#define MAXB  8

static inline int cdiv(int a, int b) { return (a + b - 1) / b; }

// Main: each lane owns one output point (coords in regs); block stages a
// 512-point slice of input positions into LDS as float4; inner loop
// broadcasts one input point per iteration to all 64 lanes (conflict-free
// LDS broadcast). Partial sums/counts combined across the 32 input slices
// via hw fp32 global atomics into workspace.
__global__ void __launch_bounds__(TPB) ball_pool_main(
    const float* __restrict__ x,        // [B, n_in]
    const float* __restrict__ inp_pos,  // [n_in, 3]
    const float* __restrict__ out_pos,  // [n_out, 3]
    float* __restrict__ ws_cnt,         // [n_out]
    float* __restrict__ ws_sum,         // [B, n_out]
    int B, int n_in, int n_out, float r2)
{
    __shared__ float4 pts[SLICE];

    const int lane = threadIdx.x & 63;
    const int wid  = threadIdx.x >> 6;
    const int slice_base = blockIdx.y * SLICE;
    const int n = min(SLICE, n_in - slice_base);

    // Stage slice of input positions into LDS (padded to float4 so the
    // inner loop is a single ds_read_b128 broadcast).
    for (int j = (int)threadIdx.x; j < n; j += TPB) {
        const int g = slice_base + j;
        pts[j] = make_float4(inp_pos[3 * g], inp_pos[3 * g + 1],
                             inp_pos[3 * g + 2], 0.0f);
    }
    __syncthreads();

    const int o = blockIdx.x * TPB + wid * 64 + lane;
    // Sentinel far position for out-of-range lanes: never matches, no
    // divergent guard needed in the hot loop.
    float ox = 1e9f, oy = 1e9f, oz = 1e9f;
    if (o < n_out) {
        ox = out_pos[3 * o];
        oy = out_pos[3 * o + 1];
        oz = out_pos[3 * o + 2];
    }

    float cnt = 0.0f;
    float s[MAXB];
#pragma unroll
    for (int b = 0; b < MAXB; ++b) s[b] = 0.0f;

    for (int j = 0; j < n; ++j) {
        const float4 p = pts[j];
        const float dx = ox - p.x;
        const float dy = oy - p.y;
        const float dz = oz - p.z;
        const float d2 = dx * dx + dy * dy + dz * dz;
        if (d2 <= r2) {               // taken ~3% of wave-iterations
            cnt += 1.0f;
            const int gi = slice_base + j;
#pragma unroll
            for (int b = 0; b < MAXB; ++b)
                if (b < B) s[b] += x[b * n_in + gi];
        }
    }

    if (o < n_out) {
        unsafeAtomicAdd(ws_cnt + o, cnt);
#pragma unroll
        for (int b = 0; b < MAXB; ++b)
            if (b < B) unsafeAtomicAdd(ws_sum + (size_t)b * n_out + o, s[b]);
    }
}

__global__ void __launch_bounds__(TPB) ball_pool_final(
    const float* __restrict__ ws_cnt,
    const float* __restrict__ ws_sum,
    float* __restrict__ out, int B, int n_out)
{
    const int i = blockIdx.x * TPB + threadIdx.x;
    if (i >= B * n_out) return;
    const int o = i % n_out;                 // ws_sum flat layout == out layout
    const float c = ws_cnt[o];
    out[i] = ws_sum[i] / (c > 0.0f ? c : 1.0f);
}

extern "C" void kernel_launch(void* const* d_in, const int* in_sizes, int n_in_args,
                              void* d_out, int out_size, void* d_ws, size_t ws_size,
                              hipStream_t stream) {
    const float* x  = (const float*)d_in[0];
    const float* ip = (const float*)d_in[1];
    const float* op = (const float*)d_in[2];
    float* out = (float*)d_out;

    const int n_in  = in_sizes[1] / 3;
    const int n_out = in_sizes[2] / 3;
    const int B     = in_sizes[0] / n_in;

    float* ws_cnt = (float*)d_ws;
    float* ws_sum = ws_cnt + n_out;

    const size_t zbytes = (size_t)(B + 1) * n_out * sizeof(float);
    hipMemsetAsync(d_ws, 0, zbytes, stream);

    const float r2 = (float)(0.05 * 0.05);   // match reference's f64->f32 rounding

    dim3 grid(cdiv(n_out, TPB), cdiv(n_in, SLICE));
    ball_pool_main<<<grid, TPB, 0, stream>>>(x, ip, op, ws_cnt, ws_sum,
                                             B, n_in, n_out, r2);

    const int tot = B * n_out;
    ball_pool_final<<<cdiv(tot, TPB), TPB, 0, stream>>>(ws_cnt, ws_sum, out,
                                                        B, n_out);
}